// Round 1
// baseline (601.304 us; speedup 1.0000x reference)
//
#include <hip/hip_runtime.h>
#include <hip/hip_bf16.h>

#define DIM_D 1024
#define DIM_KH 64
#define SEQ   2048
#define BATCH 8
#define NROWS (BATCH*SEQ)   // 16384

// ---------------------------------------------------------------------------
// Kernel 1: QKV projection.  C[m,0:192] = X[m,:] @ [Wq|Wk|Wv] + [bq|bk|bv]
// GEMM M=16384 N=192 K=1024, fp32 vector FMA. 64-row tiles, BK=32.
// ---------------------------------------------------------------------------
__global__ __launch_bounds__(256, 2) void qkv_kernel(
    const float* __restrict__ X,
    const float* __restrict__ Wq, const float* __restrict__ bq,
    const float* __restrict__ Wk, const float* __restrict__ bk,
    const float* __restrict__ Wv, const float* __restrict__ bv,
    float* __restrict__ Q, float* __restrict__ Ko, float* __restrict__ V)
{
    const int tid = threadIdx.x;
    const int m0  = blockIdx.x * 64;

    __shared__ float Xs[32][68];    // [k][row] transposed; stride 68*4=272B (16B aligned)
    __shared__ float Ws[32][196];   // [k][col]; stride 196*4=784B (16B aligned)

    const int ty = tid >> 4;   // 0..15 -> rows ty*4 .. +4
    const int tx = tid & 15;   // 0..15 -> cols tx*12 .. +12

    float acc[4][12];
    #pragma unroll
    for (int i = 0; i < 4; i++)
        #pragma unroll
        for (int j = 0; j < 12; j++) acc[i][j] = 0.f;

    for (int kk = 0; kk < DIM_D; kk += 32) {
        __syncthreads();
        // stage X tile (64 rows x 32 cols), transposed into Xs
        #pragma unroll
        for (int it = 0; it < 2; it++) {
            int idx = tid + it * 256;            // 0..511
            int r   = idx >> 3;                  // 0..63
            int c4  = idx & 7;                   // 8 float4 per row
            float4 x4 = *reinterpret_cast<const float4*>(
                X + (size_t)(m0 + r) * DIM_D + kk + c4 * 4);
            Xs[c4*4+0][r] = x4.x;
            Xs[c4*4+1][r] = x4.y;
            Xs[c4*4+2][r] = x4.z;
            Xs[c4*4+3][r] = x4.w;
        }
        // stage W tile (32 rows x 192 cols = q|k|v)
        #pragma unroll
        for (int it = 0; it < 6; it++) {
            int idx = tid + it * 256;            // 0..1535
            int r   = idx / 48;                  // 0..31
            int c4  = idx - r * 48;              // 0..47
            int cc  = c4 * 4;
            const float* src;
            if (cc < 64)       src = Wq + (size_t)(kk + r) * DIM_KH + cc;
            else if (cc < 128) src = Wk + (size_t)(kk + r) * DIM_KH + (cc - 64);
            else               src = Wv + (size_t)(kk + r) * DIM_KH + (cc - 128);
            *reinterpret_cast<float4*>(&Ws[r][cc]) =
                *reinterpret_cast<const float4*>(src);
        }
        __syncthreads();

        #pragma unroll
        for (int k = 0; k < 32; k++) {
            float4 a4 = *reinterpret_cast<const float4*>(&Xs[k][ty*4]);
            float4 b0 = *reinterpret_cast<const float4*>(&Ws[k][tx*12]);
            float4 b1 = *reinterpret_cast<const float4*>(&Ws[k][tx*12+4]);
            float4 b2 = *reinterpret_cast<const float4*>(&Ws[k][tx*12+8]);
            float a[4]  = {a4.x, a4.y, a4.z, a4.w};
            float b[12] = {b0.x,b0.y,b0.z,b0.w, b1.x,b1.y,b1.z,b1.w, b2.x,b2.y,b2.z,b2.w};
            #pragma unroll
            for (int i = 0; i < 4; i++)
                #pragma unroll
                for (int j = 0; j < 12; j++)
                    acc[i][j] = fmaf(a[i], b[j], acc[i][j]);
        }
    }

    // epilogue: bias + scatter to Q/K/V [NROWS][64]
    #pragma unroll
    for (int i = 0; i < 4; i++) {
        int m = m0 + ty*4 + i;
        #pragma unroll
        for (int j = 0; j < 12; j++) {
            int c = tx*12 + j;
            if (c < 64) {
                Q [(size_t)m*DIM_KH + c]         = acc[i][j] + bq[c];
            } else if (c < 128) {
                Ko[(size_t)m*DIM_KH + (c - 64)]  = acc[i][j] + bk[c - 64];
            } else {
                V [(size_t)m*DIM_KH + (c - 128)] = acc[i][j] + bv[c - 128];
            }
        }
    }
}

// ---------------------------------------------------------------------------
// Kernel 2: flash attention, fp32.  4 lanes per query row (16 dims each).
// Block: 256 threads = 64 q-rows.  KV tiles of 64 staged in LDS.
// ---------------------------------------------------------------------------
__global__ __launch_bounds__(256) void attn_kernel(
    const float* __restrict__ Q, const float* __restrict__ Km,
    const float* __restrict__ V, float* __restrict__ AV)
{
    const int tid  = threadIdx.x;
    const int lane = tid & 63;
    const int r    = tid >> 2;           // local q row 0..63
    const int quad = tid & 3;            // which 16-dim slice
    const int b    = blockIdx.y;
    const int row  = blockIdx.x * 64 + r;

    __shared__ float Ks[64][68];
    __shared__ float Vs[64][68];

    const float* qp = Q + ((size_t)b * SEQ + row) * DIM_KH + quad * 16;
    float qreg[16];
    {
        float4 t;
        t = ((const float4*)qp)[0]; qreg[0]=t.x;  qreg[1]=t.y;  qreg[2]=t.z;  qreg[3]=t.w;
        t = ((const float4*)qp)[1]; qreg[4]=t.x;  qreg[5]=t.y;  qreg[6]=t.z;  qreg[7]=t.w;
        t = ((const float4*)qp)[2]; qreg[8]=t.x;  qreg[9]=t.y;  qreg[10]=t.z; qreg[11]=t.w;
        t = ((const float4*)qp)[3]; qreg[12]=t.x; qreg[13]=t.y; qreg[14]=t.z; qreg[15]=t.w;
    }

    float o[16];
    #pragma unroll
    for (int i = 0; i < 16; i++) o[i] = 0.f;
    float m_run = -3.4e38f, l_run = 0.f;

    const float* Kb = Km + (size_t)b * SEQ * DIM_KH;
    const float* Vb = V  + (size_t)b * SEQ * DIM_KH;

    for (int t0 = 0; t0 < SEQ; t0 += 64) {
        __syncthreads();
        #pragma unroll
        for (int it = 0; it < 4; it++) {
            int idx = tid + it * 256;            // 0..1023
            int rr  = idx >> 4;                  // 0..63
            int c4  = idx & 15;
            *reinterpret_cast<float4*>(&Ks[rr][c4*4]) =
                *reinterpret_cast<const float4*>(Kb + (size_t)(t0+rr)*DIM_KH + c4*4);
            *reinterpret_cast<float4*>(&Vs[rr][c4*4]) =
                *reinterpret_cast<const float4*>(Vb + (size_t)(t0+rr)*DIM_KH + c4*4);
        }
        __syncthreads();

        // --- scores for 64 keys; lane owns keys j with (j&3)==quad ---
        float sreg[16];
        float mtile = -3.4e38f;
        #pragma unroll
        for (int i = 0; i < 16; i++) {
            float sv[4];
            #pragma unroll
            for (int c = 0; c < 4; c++) {
                const int j = i*4 + c;
                const float* kr = &Ks[j][quad*16];
                float4 k0 = *(const float4*)(kr+0);
                float4 k1 = *(const float4*)(kr+4);
                float4 k2 = *(const float4*)(kr+8);
                float4 k3 = *(const float4*)(kr+12);
                float p0 = fmaf(qreg[3],  k0.w, fmaf(qreg[2],  k0.z, fmaf(qreg[1],  k0.y, qreg[0]*k0.x)));
                float p1 = fmaf(qreg[7],  k1.w, fmaf(qreg[6],  k1.z, fmaf(qreg[5],  k1.y, qreg[4]*k1.x)));
                float p2 = fmaf(qreg[11], k2.w, fmaf(qreg[10], k2.z, fmaf(qreg[9],  k2.y, qreg[8]*k2.x)));
                float p3 = fmaf(qreg[15], k3.w, fmaf(qreg[14], k3.z, fmaf(qreg[13], k3.y, qreg[12]*k3.x)));
                float part = (p0 + p1) + (p2 + p3);
                part += __shfl_xor(part, 1);
                part += __shfl_xor(part, 2);
                float s = part * 0.125f;         // 1/sqrt(64)
                sv[c] = s;
                mtile = fmaxf(mtile, s);
            }
            sreg[i] = quad==0 ? sv[0] : quad==1 ? sv[1] : quad==2 ? sv[2] : sv[3];
        }

        // --- online softmax update ---
        float m_new = fmaxf(m_run, mtile);
        float scale = __expf(m_run - m_new);
        float preg[16];
        float psum = 0.f;
        #pragma unroll
        for (int i = 0; i < 16; i++) {
            preg[i] = __expf(sreg[i] - m_new);
            psum += preg[i];
        }
        psum += __shfl_xor(psum, 1);
        psum += __shfl_xor(psum, 2);
        l_run = fmaf(l_run, scale, psum);
        m_run = m_new;
        #pragma unroll
        for (int d = 0; d < 16; d++) o[d] *= scale;

        // --- PV accumulate ---
        const int base = lane & ~3;
        #pragma unroll
        for (int i = 0; i < 16; i++) {
            #pragma unroll
            for (int c = 0; c < 4; c++) {
                float p = __shfl(preg[i], base + c);
                const int j = i*4 + c;
                const float* vr = &Vs[j][quad*16];
                float4 v0 = *(const float4*)(vr+0);
                float4 v1 = *(const float4*)(vr+4);
                float4 v2 = *(const float4*)(vr+8);
                float4 v3 = *(const float4*)(vr+12);
                o[0]  = fmaf(p, v0.x, o[0]);
                o[1]  = fmaf(p, v0.y, o[1]);
                o[2]  = fmaf(p, v0.z, o[2]);
                o[3]  = fmaf(p, v0.w, o[3]);
                o[4]  = fmaf(p, v1.x, o[4]);
                o[5]  = fmaf(p, v1.y, o[5]);
                o[6]  = fmaf(p, v1.z, o[6]);
                o[7]  = fmaf(p, v1.w, o[7]);
                o[8]  = fmaf(p, v2.x, o[8]);
                o[9]  = fmaf(p, v2.y, o[9]);
                o[10] = fmaf(p, v2.z, o[10]);
                o[11] = fmaf(p, v2.w, o[11]);
                o[12] = fmaf(p, v3.x, o[12]);
                o[13] = fmaf(p, v3.y, o[13]);
                o[14] = fmaf(p, v3.z, o[14]);
                o[15] = fmaf(p, v3.w, o[15]);
            }
        }
    }

    float inv = 1.f / l_run;
    float* op = AV + ((size_t)b * SEQ + row) * DIM_KH + quad * 16;
    #pragma unroll
    for (int i = 0; i < 4; i++) {
        float4 t = { o[4*i]*inv, o[4*i+1]*inv, o[4*i+2]*inv, o[4*i+3]*inv };
        ((float4*)op)[i] = t;
    }
}

// ---------------------------------------------------------------------------
// Kernel 3: out = LayerNorm(X + AV @ Wo + bo) * gamma + beta
// 16 rows per block; Wo staged through LDS in 4 chunks of 16 K-rows.
// ---------------------------------------------------------------------------
__global__ __launch_bounds__(256, 2) void out_ln_kernel(
    const float* __restrict__ X, const float* __restrict__ AV,
    const float* __restrict__ Wo, const float* __restrict__ bo,
    const float* __restrict__ gamma, const float* __restrict__ beta,
    float* __restrict__ Out)
{
    const int tid  = threadIdx.x;
    const int row0 = blockIdx.x * 16;
    const int d0   = tid * 4;
    const int lane = tid & 63;
    const int wv   = tid >> 6;

    __shared__ float AVs[16][64];
    __shared__ float Ws[16][1024];
    __shared__ float redS[4][16];
    __shared__ float redQ[4][16];

    {
        int rr = tid >> 4, c4 = tid & 15;
        *reinterpret_cast<float4*>(&AVs[rr][c4*4]) =
            *reinterpret_cast<const float4*>(AV + ((size_t)(row0+rr))*DIM_KH + c4*4);
    }

    float acc[16][4];
    #pragma unroll
    for (int r = 0; r < 16; r++) { acc[r][0]=0.f; acc[r][1]=0.f; acc[r][2]=0.f; acc[r][3]=0.f; }

    #pragma unroll
    for (int ch = 0; ch < 4; ch++) {
        __syncthreads();
        #pragma unroll
        for (int it = 0; it < 16; it++) {
            int idx = tid + it * 256;           // 0..4095
            int rr  = idx >> 8;                 // 0..15
            int c4  = idx & 255;
            *reinterpret_cast<float4*>(&Ws[rr][c4*4]) =
                *reinterpret_cast<const float4*>(Wo + ((size_t)(ch*16+rr))*DIM_D + c4*4);
        }
        __syncthreads();
        #pragma unroll
        for (int k4 = 0; k4 < 4; k4++) {
            float4 w0 = *(const float4*)&Ws[k4*4+0][d0];
            float4 w1 = *(const float4*)&Ws[k4*4+1][d0];
            float4 w2 = *(const float4*)&Ws[k4*4+2][d0];
            float4 w3 = *(const float4*)&Ws[k4*4+3][d0];
            #pragma unroll
            for (int r = 0; r < 16; r++) {
                float4 a4 = *(const float4*)&AVs[r][ch*16 + k4*4];
                acc[r][0] = fmaf(a4.x, w0.x, acc[r][0]);
                acc[r][0] = fmaf(a4.y, w1.x, acc[r][0]);
                acc[r][0] = fmaf(a4.z, w2.x, acc[r][0]);
                acc[r][0] = fmaf(a4.w, w3.x, acc[r][0]);
                acc[r][1] = fmaf(a4.x, w0.y, acc[r][1]);
                acc[r][1] = fmaf(a4.y, w1.y, acc[r][1]);
                acc[r][1] = fmaf(a4.z, w2.y, acc[r][1]);
                acc[r][1] = fmaf(a4.w, w3.y, acc[r][1]);
                acc[r][2] = fmaf(a4.x, w0.z, acc[r][2]);
                acc[r][2] = fmaf(a4.y, w1.z, acc[r][2]);
                acc[r][2] = fmaf(a4.z, w2.z, acc[r][2]);
                acc[r][2] = fmaf(a4.w, w3.z, acc[r][2]);
                acc[r][3] = fmaf(a4.x, w0.w, acc[r][3]);
                acc[r][3] = fmaf(a4.y, w1.w, acc[r][3]);
                acc[r][3] = fmaf(a4.z, w2.w, acc[r][3]);
                acc[r][3] = fmaf(a4.w, w3.w, acc[r][3]);
            }
        }
    }

    float4 bo4 = *(const float4*)(bo + d0);
    float4 g4  = *(const float4*)(gamma + d0);
    float4 be4 = *(const float4*)(beta + d0);

    float s[16], sq[16];
    #pragma unroll
    for (int r = 0; r < 16; r++) {
        float4 x4 = *(const float4*)(X + ((size_t)(row0+r))*DIM_D + d0);
        float y0 = x4.x + acc[r][0] + bo4.x;
        float y1 = x4.y + acc[r][1] + bo4.y;
        float y2 = x4.z + acc[r][2] + bo4.z;
        float y3 = x4.w + acc[r][3] + bo4.w;
        acc[r][0]=y0; acc[r][1]=y1; acc[r][2]=y2; acc[r][3]=y3;
        s[r]  = (y0+y1)+(y2+y3);
        sq[r] = fmaf(y0,y0,fmaf(y1,y1,fmaf(y2,y2,y3*y3)));
    }
    #pragma unroll
    for (int off = 1; off < 64; off <<= 1) {
        #pragma unroll
        for (int r = 0; r < 16; r++) {
            s[r]  += __shfl_xor(s[r],  off);
            sq[r] += __shfl_xor(sq[r], off);
        }
    }
    if (lane == 0) {
        #pragma unroll
        for (int r = 0; r < 16; r++) { redS[wv][r] = s[r]; redQ[wv][r] = sq[r]; }
    }
    __syncthreads();
    #pragma unroll
    for (int r = 0; r < 16; r++) {
        float st = (redS[0][r]+redS[1][r])+(redS[2][r]+redS[3][r]);
        float qt = (redQ[0][r]+redQ[1][r])+(redQ[2][r]+redQ[3][r]);
        float mu  = st * (1.0f/1024.0f);
        float var = fmaf(qt, (1.0f/1024.0f), -mu*mu);
        float inv = rsqrtf(var + 1e-5f);
        float o0 = fmaf((acc[r][0]-mu)*inv, g4.x, be4.x);
        float o1 = fmaf((acc[r][1]-mu)*inv, g4.y, be4.y);
        float o2 = fmaf((acc[r][2]-mu)*inv, g4.z, be4.z);
        float o3 = fmaf((acc[r][3]-mu)*inv, g4.w, be4.w);
        float4 ov = {o0, o1, o2, o3};
        *reinterpret_cast<float4*>(Out + ((size_t)(row0+r))*DIM_D + d0) = ov;
    }
}

// ---------------------------------------------------------------------------
extern "C" void kernel_launch(void* const* d_in, const int* in_sizes, int n_in,
                              void* d_out, int out_size, void* d_ws, size_t ws_size,
                              hipStream_t stream)
{
    (void)in_sizes; (void)n_in; (void)out_size; (void)ws_size;
    const float* X     = (const float*)d_in[0];
    const float* Wq    = (const float*)d_in[1];
    const float* bq    = (const float*)d_in[2];
    const float* Wk    = (const float*)d_in[3];
    const float* bk    = (const float*)d_in[4];
    const float* Wv    = (const float*)d_in[5];
    const float* bv    = (const float*)d_in[6];
    const float* Wo    = (const float*)d_in[7];
    const float* bo    = (const float*)d_in[8];
    const float* gamma = (const float*)d_in[9];
    const float* beta  = (const float*)d_in[10];
    float* Out = (float*)d_out;

    float* Q  = (float*)d_ws;                      // 4 MB
    float* K  = Q + (size_t)NROWS * DIM_KH;        // 4 MB
    float* V  = K + (size_t)NROWS * DIM_KH;        // 4 MB
    float* AV = V + (size_t)NROWS * DIM_KH;        // 4 MB

    qkv_kernel<<<NROWS/64, 256, 0, stream>>>(X, Wq, bq, Wk, bk, Wv, bv, Q, K, V);
    attn_kernel<<<dim3(SEQ/64, BATCH), 256, 0, stream>>>(Q, K, V, AV);
    out_ln_kernel<<<NROWS/16, 256, 0, stream>>>(X, AV, Wo, bo, gamma, beta, Out);
}

// Round 2
// 164.054 us; speedup vs baseline: 3.6653x; 3.6653x over previous
//
#include <hip/hip_runtime.h>
#include <hip/hip_bf16.h>

#define DIM_D 1024
#define DIM_KH 64
#define SEQ   2048
#define BATCH 8
#define NROWS (BATCH*SEQ)   // 16384

typedef __attribute__((ext_vector_type(8))) short short8;
typedef __attribute__((ext_vector_type(4))) short short4v;
typedef __attribute__((ext_vector_type(4))) float floatx4;

__device__ __forceinline__ ushort f2bf(float f) {
    union { __hip_bfloat16 h; ushort u; } cv;
    cv.h = __float2bfloat16(f);
    return cv.u;
}

// ---------------------------------------------------------------------------
// Kernel 0: convert+transpose Wq|Wk|Wv (fp32 [1024][64] each) -> WT bf16 [192][1024]
// row n = o*64+nn holds W_o[:, nn] over k.
// ---------------------------------------------------------------------------
__global__ void wcvt_kernel(const float* __restrict__ Wq,
                            const float* __restrict__ Wk,
                            const float* __restrict__ Wv,
                            ushort* __restrict__ WT)
{
    const int n  = blockIdx.x;          // 0..191
    const int o  = n >> 6;
    const int nn = n & 63;
    const float* W = (o == 0) ? Wq : (o == 1) ? Wk : Wv;
    #pragma unroll
    for (int i = 0; i < 4; i++) {
        int k = threadIdx.x + i * 256;
        WT[(size_t)n * DIM_D + k] = f2bf(W[(size_t)k * DIM_KH + nn]);
    }
}

// ---------------------------------------------------------------------------
// Kernel 1: QKV projection with bf16 MFMA.
// Grid (256 m-tiles, 3 outputs). Block 256 = 4 waves; wave w owns rows 16w..16w+15.
// C tile 64x64 per block; K staged 64 at a time. Outputs bf16.
// ---------------------------------------------------------------------------
__global__ __launch_bounds__(256, 2) void qkv_mfma(
    const float* __restrict__ X, const ushort* __restrict__ WT,
    const float* __restrict__ bq, const float* __restrict__ bk,
    const float* __restrict__ bv,
    ushort* __restrict__ Qb, ushort* __restrict__ Kb, ushort* __restrict__ Vb)
{
    const int tid = threadIdx.x;
    const int m0  = blockIdx.x * 64;
    const int o   = blockIdx.y;          // 0=Q 1=K 2=V

    __shared__ ushort Xs[64 * 64];       // [row][k], XOR-swizzled
    __shared__ ushort Wls[64 * 64];      // [n][k],   XOR-swizzled

    const int w  = tid >> 6;
    const int l  = tid & 63;
    const int ql = l & 15;
    const int g  = (l >> 4) & 3;
    const int swz = (ql & 7) << 3;       // row&7 of all frag rows == ql&7

    floatx4 acc[4];
    #pragma unroll
    for (int fn = 0; fn < 4; fn++) acc[fn] = (floatx4){0.f, 0.f, 0.f, 0.f};

    for (int k0 = 0; k0 < DIM_D; k0 += 64) {
        __syncthreads();
        // stage X tile 64x64 fp32 -> bf16, swizzled
        #pragma unroll
        for (int i = 0; i < 4; i++) {
            int idx = tid + i * 256;              // 0..1023
            int row = idx >> 4;                   // 0..63
            int c4  = idx & 15;                   // float4 chunk
            float4 x4 = *reinterpret_cast<const float4*>(
                X + (size_t)(m0 + row) * DIM_D + k0 + c4 * 4);
            uint2 p;
            p.x = (uint)f2bf(x4.x) | ((uint)f2bf(x4.y) << 16);
            p.y = (uint)f2bf(x4.z) | ((uint)f2bf(x4.w) << 16);
            int addr = row * 64 + ((c4 * 4) ^ ((row & 7) << 3));
            *reinterpret_cast<uint2*>(&Xs[addr]) = p;
        }
        // stage W^T tile 64x64 bf16 (rows o*64..o*64+63 of WT), swizzled
        #pragma unroll
        for (int i = 0; i < 2; i++) {
            int idx = tid + i * 256;              // 0..511
            int n   = idx >> 3;                   // 0..63
            int ch  = idx & 7;                    // 8-elem chunk
            uint4 v = *reinterpret_cast<const uint4*>(
                WT + (size_t)(o * 64 + n) * DIM_D + k0 + ch * 8);
            int addr = n * 64 + ((ch * 8) ^ ((n & 7) << 3));
            *reinterpret_cast<uint4*>(&Wls[addr]) = v;
        }
        __syncthreads();

        #pragma unroll
        for (int kk = 0; kk < 2; kk++) {
            short8 a = *reinterpret_cast<const short8*>(
                &Xs[(16 * w + ql) * 64 + ((kk * 32 + g * 8) ^ swz)]);
            #pragma unroll
            for (int fn = 0; fn < 4; fn++) {
                short8 b = *reinterpret_cast<const short8*>(
                    &Wls[(16 * fn + ql) * 64 + ((kk * 32 + g * 8) ^ swz)]);
                acc[fn] = __builtin_amdgcn_mfma_f32_16x16x32_bf16(a, b, acc[fn], 0, 0, 0);
            }
        }
    }

    const float* bias = (o == 0) ? bq : (o == 1) ? bk : bv;
    ushort* O = (o == 0) ? Qb : (o == 1) ? Kb : Vb;
    float bvreg[4];
    #pragma unroll
    for (int fn = 0; fn < 4; fn++) bvreg[fn] = bias[16 * fn + ql];

    #pragma unroll
    for (int fn = 0; fn < 4; fn++) {
        #pragma unroll
        for (int r = 0; r < 4; r++) {
            int row = m0 + 16 * w + 4 * g + r;
            O[(size_t)row * DIM_KH + 16 * fn + ql] = f2bf(acc[fn][r] + bvreg[fn]);
        }
    }
}

// ---------------------------------------------------------------------------
// Kernel 2: flash attention, bf16 MFMA. Block 256 = 4 waves, each wave owns
// 16 q-rows independently. KV tiles of 64. S^T = mfma(K, Q^T): lane holds
// P[key][q=l&15] -> softmax in-register + shfl_xor(16,32).
// PV via key-permutation bijection: A built purely in-lane.
// ---------------------------------------------------------------------------
__global__ __launch_bounds__(256) void attn_mfma(
    const ushort* __restrict__ Qb, const ushort* __restrict__ Kb,
    const ushort* __restrict__ Vb, float* __restrict__ AV)
{
    const int tid = threadIdx.x;
    const int w   = tid >> 6;
    const int l   = tid & 63;
    const int ql  = l & 15;
    const int g   = (l >> 4) & 3;
    const int b   = blockIdx.y;
    const int q0  = blockIdx.x * 64;
    const int swzq = (ql & 7) << 3;

    __shared__ ushort Ks[64 * 64];   // [key][dim], swizzled by key
    __shared__ ushort VTs[64 * 64];  // [dim][key], swizzled by dim

    // Q fragments (B operand): lane reads Q[q0+16w+ql][kk*32 + g*8 ..+8]
    short8 qf[2];
    #pragma unroll
    for (int kk = 0; kk < 2; kk++) {
        qf[kk] = *reinterpret_cast<const short8*>(
            Qb + ((size_t)(b * SEQ + q0 + 16 * w + ql)) * DIM_KH + kk * 32 + g * 8);
    }

    floatx4 accv[4];
    #pragma unroll
    for (int fd = 0; fd < 4; fd++) accv[fd] = (floatx4){0.f, 0.f, 0.f, 0.f};
    float m_run = -3.0e38f, l_run = 0.f;

    const ushort* Kbb = Kb + (size_t)b * SEQ * DIM_KH;
    const ushort* Vbb = Vb + (size_t)b * SEQ * DIM_KH;

    for (int t0 = 0; t0 < SEQ; t0 += 64) {
        __syncthreads();
        // stage K tile [64][64], swizzled by key row
        #pragma unroll
        for (int i = 0; i < 2; i++) {
            int idx = tid + i * 256;
            int row = idx >> 3;
            int ch  = idx & 7;
            uint4 v = *reinterpret_cast<const uint4*>(
                Kbb + (size_t)(t0 + row) * DIM_KH + ch * 8);
            *reinterpret_cast<uint4*>(&Ks[row * 64 + ((ch * 8) ^ ((row & 7) << 3))]) = v;
        }
        // stage V^T tile: thread owns a 4x4 block, register transpose
        {
            int kg = tid >> 4, dg = tid & 15;
            int key0 = kg * 4, dim0 = dg * 4;
            uint2 vr[4];
            #pragma unroll
            for (int i = 0; i < 4; i++)
                vr[i] = *reinterpret_cast<const uint2*>(
                    Vbb + (size_t)(t0 + key0 + i) * DIM_KH + dim0);
            #pragma unroll
            for (int j = 0; j < 4; j++) {
                uint e0 = (j == 0) ? (vr[0].x & 0xffffu) : (j == 1) ? (vr[0].x >> 16)
                        : (j == 2) ? (vr[0].y & 0xffffu) : (vr[0].y >> 16);
                uint e1 = (j == 0) ? (vr[1].x & 0xffffu) : (j == 1) ? (vr[1].x >> 16)
                        : (j == 2) ? (vr[1].y & 0xffffu) : (vr[1].y >> 16);
                uint e2 = (j == 0) ? (vr[2].x & 0xffffu) : (j == 1) ? (vr[2].x >> 16)
                        : (j == 2) ? (vr[2].y & 0xffffu) : (vr[2].y >> 16);
                uint e3 = (j == 0) ? (vr[3].x & 0xffffu) : (j == 1) ? (vr[3].x >> 16)
                        : (j == 2) ? (vr[3].y & 0xffffu) : (vr[3].y >> 16);
                uint2 p; p.x = e0 | (e1 << 16); p.y = e2 | (e3 << 16);
                int dim = dim0 + j;
                int addr = dim * 64 + (key0 ^ ((dim & 7) << 3));
                *reinterpret_cast<uint2*>(&VTs[addr]) = p;
            }
        }
        __syncthreads();

        // QK^T: S^T fragments, D[key][q]
        floatx4 sfrag[4];
        #pragma unroll
        for (int f = 0; f < 4; f++) {
            sfrag[f] = (floatx4){0.f, 0.f, 0.f, 0.f};
            #pragma unroll
            for (int kk = 0; kk < 2; kk++) {
                short8 a = *reinterpret_cast<const short8*>(
                    &Ks[(16 * f + ql) * 64 + ((kk * 32 + g * 8) ^ swzq)]);
                sfrag[f] = __builtin_amdgcn_mfma_f32_16x16x32_bf16(a, qf[kk], sfrag[f], 0, 0, 0);
            }
        }

        // online softmax (scores scaled by 1/8 inside exp)
        float mt = -3.0e38f;
        #pragma unroll
        for (int f = 0; f < 4; f++)
            #pragma unroll
            for (int r = 0; r < 4; r++) mt = fmaxf(mt, sfrag[f][r]);
        mt = fmaxf(mt, __shfl_xor(mt, 16));
        mt = fmaxf(mt, __shfl_xor(mt, 32));
        float m_new = fmaxf(m_run, mt);
        float sc = __expf((m_run - m_new) * 0.125f);
        float psum = 0.f;
        ushort pb[4][4];
        #pragma unroll
        for (int f = 0; f < 4; f++)
            #pragma unroll
            for (int r = 0; r < 4; r++) {
                float p = __expf((sfrag[f][r] - m_new) * 0.125f);
                pb[f][r] = f2bf(p);
                psum += p;
            }
        psum += __shfl_xor(psum, 16);
        psum += __shfl_xor(psum, 32);
        l_run = l_run * sc + psum;
        m_run = m_new;

        // rescale accumulators (per output row q=4g+r -> fetch that q's scale)
        float s0 = __shfl(sc, 4 * g + 0);
        float s1 = __shfl(sc, 4 * g + 1);
        float s2 = __shfl(sc, 4 * g + 2);
        float s3 = __shfl(sc, 4 * g + 3);
        #pragma unroll
        for (int fd = 0; fd < 4; fd++) {
            accv[fd][0] *= s0; accv[fd][1] *= s1;
            accv[fd][2] *= s2; accv[fd][3] *= s3;
        }

        // PV: A-frags in-lane via key bijection key(8g+j) = j<4 ? base+4g+j : base+16+4g+(j-4)
        short8 pa_lo, pa_hi;
        pa_lo[0] = (short)pb[0][0]; pa_lo[1] = (short)pb[0][1];
        pa_lo[2] = (short)pb[0][2]; pa_lo[3] = (short)pb[0][3];
        pa_lo[4] = (short)pb[1][0]; pa_lo[5] = (short)pb[1][1];
        pa_lo[6] = (short)pb[1][2]; pa_lo[7] = (short)pb[1][3];
        pa_hi[0] = (short)pb[2][0]; pa_hi[1] = (short)pb[2][1];
        pa_hi[2] = (short)pb[2][2]; pa_hi[3] = (short)pb[2][3];
        pa_hi[4] = (short)pb[3][0]; pa_hi[5] = (short)pb[3][1];
        pa_hi[6] = (short)pb[3][2]; pa_hi[7] = (short)pb[3][3];

        #pragma unroll
        for (int fd = 0; fd < 4; fd++) {
            int dim = 16 * fd + ql;
            int base = dim * 64;
            int sw = (dim & 7) << 3;
            short4v v0 = *reinterpret_cast<const short4v*>(&VTs[base + ((4 * g) ^ sw)]);
            short4v v1 = *reinterpret_cast<const short4v*>(&VTs[base + ((16 + 4 * g) ^ sw)]);
            short8 bb;
            bb[0] = v0[0]; bb[1] = v0[1]; bb[2] = v0[2]; bb[3] = v0[3];
            bb[4] = v1[0]; bb[5] = v1[1]; bb[6] = v1[2]; bb[7] = v1[3];
            accv[fd] = __builtin_amdgcn_mfma_f32_16x16x32_bf16(pa_lo, bb, accv[fd], 0, 0, 0);
            short4v v2 = *reinterpret_cast<const short4v*>(&VTs[base + ((32 + 4 * g) ^ sw)]);
            short4v v3 = *reinterpret_cast<const short4v*>(&VTs[base + ((48 + 4 * g) ^ sw)]);
            short8 bb2;
            bb2[0] = v2[0]; bb2[1] = v2[1]; bb2[2] = v2[2]; bb2[3] = v2[3];
            bb2[4] = v3[0]; bb2[5] = v3[1]; bb2[6] = v3[2]; bb2[7] = v3[3];
            accv[fd] = __builtin_amdgcn_mfma_f32_16x16x32_bf16(pa_hi, bb2, accv[fd], 0, 0, 0);
        }
    }

    float inv = 1.0f / l_run;
    float i0 = __shfl(inv, 4 * g + 0);
    float i1 = __shfl(inv, 4 * g + 1);
    float i2 = __shfl(inv, 4 * g + 2);
    float i3 = __shfl(inv, 4 * g + 3);
    #pragma unroll
    for (int fd = 0; fd < 4; fd++) {
        int col = 16 * fd + ql;
        size_t rbase = (size_t)(b * SEQ + q0 + 16 * w + 4 * g);
        AV[(rbase + 0) * DIM_KH + col] = accv[fd][0] * i0;
        AV[(rbase + 1) * DIM_KH + col] = accv[fd][1] * i1;
        AV[(rbase + 2) * DIM_KH + col] = accv[fd][2] * i2;
        AV[(rbase + 3) * DIM_KH + col] = accv[fd][3] * i3;
    }
}

// ---------------------------------------------------------------------------
// Kernel 3: out = LayerNorm(X + AV @ Wo + bo) * gamma + beta   (unchanged fp32)
// ---------------------------------------------------------------------------
__global__ __launch_bounds__(256, 2) void out_ln_kernel(
    const float* __restrict__ X, const float* __restrict__ AV,
    const float* __restrict__ Wo, const float* __restrict__ bo,
    const float* __restrict__ gamma, const float* __restrict__ beta,
    float* __restrict__ Out)
{
    const int tid  = threadIdx.x;
    const int row0 = blockIdx.x * 16;
    const int d0   = tid * 4;
    const int lane = tid & 63;
    const int wv   = tid >> 6;

    __shared__ float AVs[16][64];
    __shared__ float Ws[16][1024];
    __shared__ float redS[4][16];
    __shared__ float redQ[4][16];

    {
        int rr = tid >> 4, c4 = tid & 15;
        *reinterpret_cast<float4*>(&AVs[rr][c4*4]) =
            *reinterpret_cast<const float4*>(AV + ((size_t)(row0+rr))*DIM_KH + c4*4);
    }

    float acc[16][4];
    #pragma unroll
    for (int r = 0; r < 16; r++) { acc[r][0]=0.f; acc[r][1]=0.f; acc[r][2]=0.f; acc[r][3]=0.f; }

    #pragma unroll
    for (int ch = 0; ch < 4; ch++) {
        __syncthreads();
        #pragma unroll
        for (int it = 0; it < 16; it++) {
            int idx = tid + it * 256;
            int rr  = idx >> 8;
            int c4  = idx & 255;
            *reinterpret_cast<float4*>(&Ws[rr][c4*4]) =
                *reinterpret_cast<const float4*>(Wo + ((size_t)(ch*16+rr))*DIM_D + c4*4);
        }
        __syncthreads();
        #pragma unroll
        for (int k4 = 0; k4 < 4; k4++) {
            float4 w0 = *(const float4*)&Ws[k4*4+0][d0];
            float4 w1 = *(const float4*)&Ws[k4*4+1][d0];
            float4 w2 = *(const float4*)&Ws[k4*4+2][d0];
            float4 w3 = *(const float4*)&Ws[k4*4+3][d0];
            #pragma unroll
            for (int r = 0; r < 16; r++) {
                float4 a4 = *(const float4*)&AVs[r][ch*16 + k4*4];
                acc[r][0] = fmaf(a4.x, w0.x, acc[r][0]);
                acc[r][0] = fmaf(a4.y, w1.x, acc[r][0]);
                acc[r][0] = fmaf(a4.z, w2.x, acc[r][0]);
                acc[r][0] = fmaf(a4.w, w3.x, acc[r][0]);
                acc[r][1] = fmaf(a4.x, w0.y, acc[r][1]);
                acc[r][1] = fmaf(a4.y, w1.y, acc[r][1]);
                acc[r][1] = fmaf(a4.z, w2.y, acc[r][1]);
                acc[r][1] = fmaf(a4.w, w3.y, acc[r][1]);
                acc[r][2] = fmaf(a4.x, w0.z, acc[r][2]);
                acc[r][2] = fmaf(a4.y, w1.z, acc[r][2]);
                acc[r][2] = fmaf(a4.z, w2.z, acc[r][2]);
                acc[r][2] = fmaf(a4.w, w3.z, acc[r][2]);
                acc[r][3] = fmaf(a4.x, w0.w, acc[r][3]);
                acc[r][3] = fmaf(a4.y, w1.w, acc[r][3]);
                acc[r][3] = fmaf(a4.z, w2.w, acc[r][3]);
                acc[r][3] = fmaf(a4.w, w3.w, acc[r][3]);
            }
        }
    }

    float4 bo4 = *(const float4*)(bo + d0);
    float4 g4  = *(const float4*)(gamma + d0);
    float4 be4 = *(const float4*)(beta + d0);

    float s[16], sq[16];
    #pragma unroll
    for (int r = 0; r < 16; r++) {
        float4 x4 = *(const float4*)(X + ((size_t)(row0+r))*DIM_D + d0);
        float y0 = x4.x + acc[r][0] + bo4.x;
        float y1 = x4.y + acc[r][1] + bo4.y;
        float y2 = x4.z + acc[r][2] + bo4.z;
        float y3 = x4.w + acc[r][3] + bo4.w;
        acc[r][0]=y0; acc[r][1]=y1; acc[r][2]=y2; acc[r][3]=y3;
        s[r]  = (y0+y1)+(y2+y3);
        sq[r] = fmaf(y0,y0,fmaf(y1,y1,fmaf(y2,y2,y3*y3)));
    }
    #pragma unroll
    for (int off = 1; off < 64; off <<= 1) {
        #pragma unroll
        for (int r = 0; r < 16; r++) {
            s[r]  += __shfl_xor(s[r],  off);
            sq[r] += __shfl_xor(sq[r], off);
        }
    }
    if (lane == 0) {
        #pragma unroll
        for (int r = 0; r < 16; r++) { redS[wv][r] = s[r]; redQ[wv][r] = sq[r]; }
    }
    __syncthreads();
    #pragma unroll
    for (int r = 0; r < 16; r++) {
        float st = (redS[0][r]+redS[1][r])+(redS[2][r]+redS[3][r]);
        float qt = (redQ[0][r]+redQ[1][r])+(redQ[2][r]+redQ[3][r]);
        float mu  = st * (1.0f/1024.0f);
        float var = fmaf(qt, (1.0f/1024.0f), -mu*mu);
        float inv = rsqrtf(var + 1e-5f);
        float o0 = fmaf((acc[r][0]-mu)*inv, g4.x, be4.x);
        float o1 = fmaf((acc[r][1]-mu)*inv, g4.y, be4.y);
        float o2 = fmaf((acc[r][2]-mu)*inv, g4.z, be4.z);
        float o3 = fmaf((acc[r][3]-mu)*inv, g4.w, be4.w);
        float4 ov = {o0, o1, o2, o3};
        *reinterpret_cast<float4*>(Out + ((size_t)(row0+r))*DIM_D + d0) = ov;
    }
}

// ---------------------------------------------------------------------------
extern "C" void kernel_launch(void* const* d_in, const int* in_sizes, int n_in,
                              void* d_out, int out_size, void* d_ws, size_t ws_size,
                              hipStream_t stream)
{
    (void)in_sizes; (void)n_in; (void)out_size; (void)ws_size;
    const float* X     = (const float*)d_in[0];
    const float* Wq    = (const float*)d_in[1];
    const float* bq    = (const float*)d_in[2];
    const float* Wk    = (const float*)d_in[3];
    const float* bk    = (const float*)d_in[4];
    const float* Wv    = (const float*)d_in[5];
    const float* bv    = (const float*)d_in[6];
    const float* Wo    = (const float*)d_in[7];
    const float* bo    = (const float*)d_in[8];
    const float* gamma = (const float*)d_in[9];
    const float* beta  = (const float*)d_in[10];
    float* Out = (float*)d_out;

    ushort* Qb  = (ushort*)d_ws;                        // 2 MB bf16
    ushort* Kb  = Qb + (size_t)NROWS * DIM_KH;          // 2 MB
    ushort* Vb  = Kb + (size_t)NROWS * DIM_KH;          // 2 MB
    float*  AV  = (float*)(Vb + (size_t)NROWS * DIM_KH);// 4 MB fp32
    ushort* WT  = (ushort*)(AV + (size_t)NROWS * DIM_KH); // 384 KB bf16

    wcvt_kernel<<<192, 256, 0, stream>>>(Wq, Wk, Wv, WT);
    qkv_mfma<<<dim3(256, 3), 256, 0, stream>>>(X, WT, bq, bk, bv, Qb, Kb, Vb);
    attn_mfma<<<dim3(SEQ/64, BATCH), 256, 0, stream>>>(Qb, Kb, Vb, AV);
    out_ln_kernel<<<NROWS/16, 256, 0, stream>>>(X, AV, Wo, bo, gamma, beta, Out);
}

// Round 3
// 153.975 us; speedup vs baseline: 3.9052x; 1.0655x over previous
//
#include <hip/hip_runtime.h>
#include <hip/hip_bf16.h>

#define DIM_D 1024
#define DIM_KH 64
#define SEQ   2048
#define BATCH 8
#define NROWS (BATCH*SEQ)   // 16384

typedef __attribute__((ext_vector_type(8))) short short8;
typedef __attribute__((ext_vector_type(4))) short short4v;
typedef __attribute__((ext_vector_type(4))) float floatx4;

__device__ __forceinline__ ushort f2bf(float f) {
    union { __hip_bfloat16 h; ushort u; } cv;
    cv.h = __float2bfloat16(f);
    return cv.u;
}

// ---------------------------------------------------------------------------
// Kernel 0a: convert+transpose Wq|Wk|Wv (fp32 [1024][64] each) -> WT bf16 [192][1024]
// ---------------------------------------------------------------------------
__global__ void wcvt_kernel(const float* __restrict__ Wq,
                            const float* __restrict__ Wk,
                            const float* __restrict__ Wv,
                            ushort* __restrict__ WT)
{
    const int n  = blockIdx.x;          // 0..191
    const int o  = n >> 6;
    const int nn = n & 63;
    const float* W = (o == 0) ? Wq : (o == 1) ? Wk : Wv;
    #pragma unroll
    for (int i = 0; i < 4; i++) {
        int k = threadIdx.x + i * 256;
        WT[(size_t)n * DIM_D + k] = f2bf(W[(size_t)k * DIM_KH + nn]);
    }
}

// ---------------------------------------------------------------------------
// Kernel 0b: convert+transpose Wo (fp32 [64][1024]) -> WoT bf16 [1024][64]
// ---------------------------------------------------------------------------
__global__ void wocvt_kernel(const float* __restrict__ Wo, ushort* __restrict__ WoT)
{
    const int tid = threadIdx.x;
    const int n = blockIdx.x * 4 + (tid >> 6);   // 0..1023
    const int k = tid & 63;
    WoT[(size_t)n * DIM_KH + k] = f2bf(Wo[(size_t)k * DIM_D + n]);
}

// ---------------------------------------------------------------------------
// Kernel 1: QKV projection with bf16 MFMA. (unchanged from round 2)
// ---------------------------------------------------------------------------
__global__ __launch_bounds__(256, 2) void qkv_mfma(
    const float* __restrict__ X, const ushort* __restrict__ WT,
    const float* __restrict__ bq, const float* __restrict__ bk,
    const float* __restrict__ bv,
    ushort* __restrict__ Qb, ushort* __restrict__ Kb, ushort* __restrict__ Vb)
{
    const int tid = threadIdx.x;
    const int m0  = blockIdx.x * 64;
    const int o   = blockIdx.y;          // 0=Q 1=K 2=V

    __shared__ ushort Xs[64 * 64];       // [row][k], XOR-swizzled
    __shared__ ushort Wls[64 * 64];      // [n][k],   XOR-swizzled

    const int w  = tid >> 6;
    const int l  = tid & 63;
    const int ql = l & 15;
    const int g  = (l >> 4) & 3;
    const int swz = (ql & 7) << 3;

    floatx4 acc[4];
    #pragma unroll
    for (int fn = 0; fn < 4; fn++) acc[fn] = (floatx4){0.f, 0.f, 0.f, 0.f};

    for (int k0 = 0; k0 < DIM_D; k0 += 64) {
        __syncthreads();
        #pragma unroll
        for (int i = 0; i < 4; i++) {
            int idx = tid + i * 256;
            int row = idx >> 4;
            int c4  = idx & 15;
            float4 x4 = *reinterpret_cast<const float4*>(
                X + (size_t)(m0 + row) * DIM_D + k0 + c4 * 4);
            uint2 p;
            p.x = (uint)f2bf(x4.x) | ((uint)f2bf(x4.y) << 16);
            p.y = (uint)f2bf(x4.z) | ((uint)f2bf(x4.w) << 16);
            int addr = row * 64 + ((c4 * 4) ^ ((row & 7) << 3));
            *reinterpret_cast<uint2*>(&Xs[addr]) = p;
        }
        #pragma unroll
        for (int i = 0; i < 2; i++) {
            int idx = tid + i * 256;
            int n   = idx >> 3;
            int ch  = idx & 7;
            uint4 v = *reinterpret_cast<const uint4*>(
                WT + (size_t)(o * 64 + n) * DIM_D + k0 + ch * 8);
            int addr = n * 64 + ((ch * 8) ^ ((n & 7) << 3));
            *reinterpret_cast<uint4*>(&Wls[addr]) = v;
        }
        __syncthreads();

        #pragma unroll
        for (int kk = 0; kk < 2; kk++) {
            short8 a = *reinterpret_cast<const short8*>(
                &Xs[(16 * w + ql) * 64 + ((kk * 32 + g * 8) ^ swz)]);
            #pragma unroll
            for (int fn = 0; fn < 4; fn++) {
                short8 b = *reinterpret_cast<const short8*>(
                    &Wls[(16 * fn + ql) * 64 + ((kk * 32 + g * 8) ^ swz)]);
                acc[fn] = __builtin_amdgcn_mfma_f32_16x16x32_bf16(a, b, acc[fn], 0, 0, 0);
            }
        }
    }

    const float* bias = (o == 0) ? bq : (o == 1) ? bk : bv;
    ushort* O = (o == 0) ? Qb : (o == 1) ? Kb : Vb;
    float bvreg[4];
    #pragma unroll
    for (int fn = 0; fn < 4; fn++) bvreg[fn] = bias[16 * fn + ql];

    #pragma unroll
    for (int fn = 0; fn < 4; fn++) {
        #pragma unroll
        for (int r = 0; r < 4; r++) {
            int row = m0 + 16 * w + 4 * g + r;
            O[(size_t)row * DIM_KH + 16 * fn + ql] = f2bf(acc[fn][r] + bvreg[fn]);
        }
    }
}

// ---------------------------------------------------------------------------
// Kernel 2: flash attention, bf16 MFMA. AV output now bf16.
// ---------------------------------------------------------------------------
__global__ __launch_bounds__(256) void attn_mfma(
    const ushort* __restrict__ Qb, const ushort* __restrict__ Kb,
    const ushort* __restrict__ Vb, ushort* __restrict__ AVb)
{
    const int tid = threadIdx.x;
    const int w   = tid >> 6;
    const int l   = tid & 63;
    const int ql  = l & 15;
    const int g   = (l >> 4) & 3;
    const int b   = blockIdx.y;
    const int q0  = blockIdx.x * 64;
    const int swzq = (ql & 7) << 3;

    __shared__ ushort Ks[64 * 64];   // [key][dim], swizzled by key
    __shared__ ushort VTs[64 * 64];  // [dim][key], swizzled by dim

    short8 qf[2];
    #pragma unroll
    for (int kk = 0; kk < 2; kk++) {
        qf[kk] = *reinterpret_cast<const short8*>(
            Qb + ((size_t)(b * SEQ + q0 + 16 * w + ql)) * DIM_KH + kk * 32 + g * 8);
    }

    floatx4 accv[4];
    #pragma unroll
    for (int fd = 0; fd < 4; fd++) accv[fd] = (floatx4){0.f, 0.f, 0.f, 0.f};
    float m_run = -3.0e38f, l_run = 0.f;

    const ushort* Kbb = Kb + (size_t)b * SEQ * DIM_KH;
    const ushort* Vbb = Vb + (size_t)b * SEQ * DIM_KH;

    for (int t0 = 0; t0 < SEQ; t0 += 64) {
        __syncthreads();
        #pragma unroll
        for (int i = 0; i < 2; i++) {
            int idx = tid + i * 256;
            int row = idx >> 3;
            int ch  = idx & 7;
            uint4 v = *reinterpret_cast<const uint4*>(
                Kbb + (size_t)(t0 + row) * DIM_KH + ch * 8);
            *reinterpret_cast<uint4*>(&Ks[row * 64 + ((ch * 8) ^ ((row & 7) << 3))]) = v;
        }
        {
            int kg = tid >> 4, dg = tid & 15;
            int key0 = kg * 4, dim0 = dg * 4;
            uint2 vr[4];
            #pragma unroll
            for (int i = 0; i < 4; i++)
                vr[i] = *reinterpret_cast<const uint2*>(
                    Vbb + (size_t)(t0 + key0 + i) * DIM_KH + dim0);
            #pragma unroll
            for (int j = 0; j < 4; j++) {
                uint e0 = (j == 0) ? (vr[0].x & 0xffffu) : (j == 1) ? (vr[0].x >> 16)
                        : (j == 2) ? (vr[0].y & 0xffffu) : (vr[0].y >> 16);
                uint e1 = (j == 0) ? (vr[1].x & 0xffffu) : (j == 1) ? (vr[1].x >> 16)
                        : (j == 2) ? (vr[1].y & 0xffffu) : (vr[1].y >> 16);
                uint e2 = (j == 0) ? (vr[2].x & 0xffffu) : (j == 1) ? (vr[2].x >> 16)
                        : (j == 2) ? (vr[2].y & 0xffffu) : (vr[2].y >> 16);
                uint e3 = (j == 0) ? (vr[3].x & 0xffffu) : (j == 1) ? (vr[3].x >> 16)
                        : (j == 2) ? (vr[3].y & 0xffffu) : (vr[3].y >> 16);
                uint2 p; p.x = e0 | (e1 << 16); p.y = e2 | (e3 << 16);
                int dim = dim0 + j;
                int addr = dim * 64 + (key0 ^ ((dim & 7) << 3));
                *reinterpret_cast<uint2*>(&VTs[addr]) = p;
            }
        }
        __syncthreads();

        floatx4 sfrag[4];
        #pragma unroll
        for (int f = 0; f < 4; f++) {
            sfrag[f] = (floatx4){0.f, 0.f, 0.f, 0.f};
            #pragma unroll
            for (int kk = 0; kk < 2; kk++) {
                short8 a = *reinterpret_cast<const short8*>(
                    &Ks[(16 * f + ql) * 64 + ((kk * 32 + g * 8) ^ swzq)]);
                sfrag[f] = __builtin_amdgcn_mfma_f32_16x16x32_bf16(a, qf[kk], sfrag[f], 0, 0, 0);
            }
        }

        float mt = -3.0e38f;
        #pragma unroll
        for (int f = 0; f < 4; f++)
            #pragma unroll
            for (int r = 0; r < 4; r++) mt = fmaxf(mt, sfrag[f][r]);
        mt = fmaxf(mt, __shfl_xor(mt, 16));
        mt = fmaxf(mt, __shfl_xor(mt, 32));
        float m_new = fmaxf(m_run, mt);
        float sc = __expf((m_run - m_new) * 0.125f);
        float psum = 0.f;
        ushort pb[4][4];
        #pragma unroll
        for (int f = 0; f < 4; f++)
            #pragma unroll
            for (int r = 0; r < 4; r++) {
                float p = __expf((sfrag[f][r] - m_new) * 0.125f);
                pb[f][r] = f2bf(p);
                psum += p;
            }
        psum += __shfl_xor(psum, 16);
        psum += __shfl_xor(psum, 32);
        l_run = l_run * sc + psum;
        m_run = m_new;

        float s0 = __shfl(sc, 4 * g + 0);
        float s1 = __shfl(sc, 4 * g + 1);
        float s2 = __shfl(sc, 4 * g + 2);
        float s3 = __shfl(sc, 4 * g + 3);
        #pragma unroll
        for (int fd = 0; fd < 4; fd++) {
            accv[fd][0] *= s0; accv[fd][1] *= s1;
            accv[fd][2] *= s2; accv[fd][3] *= s3;
        }

        short8 pa_lo, pa_hi;
        pa_lo[0] = (short)pb[0][0]; pa_lo[1] = (short)pb[0][1];
        pa_lo[2] = (short)pb[0][2]; pa_lo[3] = (short)pb[0][3];
        pa_lo[4] = (short)pb[1][0]; pa_lo[5] = (short)pb[1][1];
        pa_lo[6] = (short)pb[1][2]; pa_lo[7] = (short)pb[1][3];
        pa_hi[0] = (short)pb[2][0]; pa_hi[1] = (short)pb[2][1];
        pa_hi[2] = (short)pb[2][2]; pa_hi[3] = (short)pb[2][3];
        pa_hi[4] = (short)pb[3][0]; pa_hi[5] = (short)pb[3][1];
        pa_hi[6] = (short)pb[3][2]; pa_hi[7] = (short)pb[3][3];

        #pragma unroll
        for (int fd = 0; fd < 4; fd++) {
            int dim = 16 * fd + ql;
            int base = dim * 64;
            int sw = (dim & 7) << 3;
            short4v v0 = *reinterpret_cast<const short4v*>(&VTs[base + ((4 * g) ^ sw)]);
            short4v v1 = *reinterpret_cast<const short4v*>(&VTs[base + ((16 + 4 * g) ^ sw)]);
            short8 bb;
            bb[0] = v0[0]; bb[1] = v0[1]; bb[2] = v0[2]; bb[3] = v0[3];
            bb[4] = v1[0]; bb[5] = v1[1]; bb[6] = v1[2]; bb[7] = v1[3];
            accv[fd] = __builtin_amdgcn_mfma_f32_16x16x32_bf16(pa_lo, bb, accv[fd], 0, 0, 0);
            short4v v2 = *reinterpret_cast<const short4v*>(&VTs[base + ((32 + 4 * g) ^ sw)]);
            short4v v3 = *reinterpret_cast<const short4v*>(&VTs[base + ((48 + 4 * g) ^ sw)]);
            short8 bb2;
            bb2[0] = v2[0]; bb2[1] = v2[1]; bb2[2] = v2[2]; bb2[3] = v2[3];
            bb2[4] = v3[0]; bb2[5] = v3[1]; bb2[6] = v3[2]; bb2[7] = v3[3];
            accv[fd] = __builtin_amdgcn_mfma_f32_16x16x32_bf16(pa_hi, bb2, accv[fd], 0, 0, 0);
        }
    }

    float inv = 1.0f / l_run;
    float i0 = __shfl(inv, 4 * g + 0);
    float i1 = __shfl(inv, 4 * g + 1);
    float i2 = __shfl(inv, 4 * g + 2);
    float i3 = __shfl(inv, 4 * g + 3);
    #pragma unroll
    for (int fd = 0; fd < 4; fd++) {
        int col = 16 * fd + ql;
        size_t rbase = (size_t)(b * SEQ + q0 + 16 * w + 4 * g);
        AVb[(rbase + 0) * DIM_KH + col] = f2bf(accv[fd][0] * i0);
        AVb[(rbase + 1) * DIM_KH + col] = f2bf(accv[fd][1] * i1);
        AVb[(rbase + 2) * DIM_KH + col] = f2bf(accv[fd][2] * i2);
        AVb[(rbase + 3) * DIM_KH + col] = f2bf(accv[fd][3] * i3);
    }
}

// ---------------------------------------------------------------------------
// Kernel 3: out = LayerNorm(X + AV @ Wo + bo) * gamma + beta, bf16 MFMA.
// 16 rows/block (row = blk*16 + ql), 4 waves x 256 cols. K=64: no K-loop,
// operands straight from global (WoT is 128 KB -> L2-resident).
// Swapped operands: mfma(WoT_frag, AV_frag) -> lane holds 4 consecutive
// cols of one row per frag -> float4 residual load + store, in-register LN.
// ---------------------------------------------------------------------------
__global__ __launch_bounds__(256) void out_mfma(
    const float* __restrict__ X, const ushort* __restrict__ AVb,
    const ushort* __restrict__ WoT, const float* __restrict__ bo,
    const float* __restrict__ gamma, const float* __restrict__ beta,
    float* __restrict__ Out)
{
    const int tid = threadIdx.x;
    const int w   = tid >> 6;
    const int l   = tid & 63;
    const int ql  = l & 15;
    const int g   = (l >> 4) & 3;
    const int row = blockIdx.x * 16 + ql;
    const int c0  = w * 256;

    __shared__ float redS[4][16];
    __shared__ float redQ[4][16];

    // B-frags: AV row `row`, k contiguous
    short8 bf0 = *reinterpret_cast<const short8*>(AVb + (size_t)row * DIM_KH + g * 8);
    short8 bf1 = *reinterpret_cast<const short8*>(AVb + (size_t)row * DIM_KH + 32 + g * 8);

    floatx4 acc[16];
    #pragma unroll
    for (int ft = 0; ft < 16; ft++) {
        const ushort* ap = WoT + (size_t)(c0 + 16 * ft + ql) * DIM_KH + g * 8;
        short8 a0 = *reinterpret_cast<const short8*>(ap);
        short8 a1 = *reinterpret_cast<const short8*>(ap + 32);
        floatx4 z = (floatx4){0.f, 0.f, 0.f, 0.f};
        z = __builtin_amdgcn_mfma_f32_16x16x32_bf16(a0, bf0, z, 0, 0, 0);
        z = __builtin_amdgcn_mfma_f32_16x16x32_bf16(a1, bf1, z, 0, 0, 0);
        acc[ft] = z;
    }

    // residual + bias, accumulate row stats
    float s = 0.f, sq = 0.f;
    #pragma unroll
    for (int ft = 0; ft < 16; ft++) {
        int col = c0 + 16 * ft + 4 * g;
        float4 x4 = *reinterpret_cast<const float4*>(X + (size_t)row * DIM_D + col);
        float4 b4 = *reinterpret_cast<const float4*>(bo + col);
        float y0 = acc[ft][0] + x4.x + b4.x;
        float y1 = acc[ft][1] + x4.y + b4.y;
        float y2 = acc[ft][2] + x4.z + b4.z;
        float y3 = acc[ft][3] + x4.w + b4.w;
        acc[ft][0] = y0; acc[ft][1] = y1; acc[ft][2] = y2; acc[ft][3] = y3;
        s  += (y0 + y1) + (y2 + y3);
        sq += fmaf(y0, y0, fmaf(y1, y1, fmaf(y2, y2, y3 * y3)));
    }
    s  += __shfl_xor(s, 16);  s  += __shfl_xor(s, 32);
    sq += __shfl_xor(sq, 16); sq += __shfl_xor(sq, 32);
    if (l < 16) { redS[w][ql] = s; redQ[w][ql] = sq; }
    __syncthreads();
    float st = (redS[0][ql] + redS[1][ql]) + (redS[2][ql] + redS[3][ql]);
    float qt = (redQ[0][ql] + redQ[1][ql]) + (redQ[2][ql] + redQ[3][ql]);
    float mu  = st * (1.0f / 1024.0f);
    float var = fmaf(qt, (1.0f / 1024.0f), -mu * mu);
    float inv = rsqrtf(var + 1e-5f);

    #pragma unroll
    for (int ft = 0; ft < 16; ft++) {
        int col = c0 + 16 * ft + 4 * g;
        float4 g4  = *reinterpret_cast<const float4*>(gamma + col);
        float4 be4 = *reinterpret_cast<const float4*>(beta + col);
        float4 ov;
        ov.x = fmaf((acc[ft][0] - mu) * inv, g4.x, be4.x);
        ov.y = fmaf((acc[ft][1] - mu) * inv, g4.y, be4.y);
        ov.z = fmaf((acc[ft][2] - mu) * inv, g4.z, be4.z);
        ov.w = fmaf((acc[ft][3] - mu) * inv, g4.w, be4.w);
        *reinterpret_cast<float4*>(Out + (size_t)row * DIM_D + col) = ov;
    }
}

// ---------------------------------------------------------------------------
extern "C" void kernel_launch(void* const* d_in, const int* in_sizes, int n_in,
                              void* d_out, int out_size, void* d_ws, size_t ws_size,
                              hipStream_t stream)
{
    (void)in_sizes; (void)n_in; (void)out_size; (void)ws_size;
    const float* X     = (const float*)d_in[0];
    const float* Wq    = (const float*)d_in[1];
    const float* bq    = (const float*)d_in[2];
    const float* Wk    = (const float*)d_in[3];
    const float* bk    = (const float*)d_in[4];
    const float* Wv    = (const float*)d_in[5];
    const float* bv    = (const float*)d_in[6];
    const float* Wo    = (const float*)d_in[7];
    const float* bo    = (const float*)d_in[8];
    const float* gamma = (const float*)d_in[9];
    const float* beta  = (const float*)d_in[10];
    float* Out = (float*)d_out;

    ushort* Qb  = (ushort*)d_ws;                          // 2 MB bf16
    ushort* Kb  = Qb + (size_t)NROWS * DIM_KH;            // 2 MB
    ushort* Vb  = Kb + (size_t)NROWS * DIM_KH;            // 2 MB
    ushort* AVb = Vb + (size_t)NROWS * DIM_KH;            // 2 MB
    ushort* WT  = AVb + (size_t)NROWS * DIM_KH;           // 384 KB
    ushort* WoT = WT + (size_t)192 * DIM_D;               // 128 KB

    wcvt_kernel<<<192, 256, 0, stream>>>(Wq, Wk, Wv, WT);
    wocvt_kernel<<<256, 256, 0, stream>>>(Wo, WoT);
    qkv_mfma<<<dim3(256, 3), 256, 0, stream>>>(X, WT, bq, bk, bv, Qb, Kb, Vb);
    attn_mfma<<<dim3(SEQ/64, BATCH), 256, 0, stream>>>(Qb, Kb, Vb, AVb);
    out_mfma<<<NROWS/16, 256, 0, stream>>>(X, AVb, WoT, bo, gamma, beta, Out);
}

// Round 4
// 122.580 us; speedup vs baseline: 4.9054x; 1.2561x over previous
//
#include <hip/hip_runtime.h>
#include <hip/hip_bf16.h>

#define DIM_D 1024
#define DIM_KH 64
#define SEQ   2048
#define BATCH 8
#define NROWS (BATCH*SEQ)   // 16384
#define KVSPLIT 4
#define KEYS_PER_SPLIT (SEQ/KVSPLIT)   // 512

typedef __attribute__((ext_vector_type(8))) short short8;
typedef __attribute__((ext_vector_type(4))) short short4v;
typedef __attribute__((ext_vector_type(4))) float floatx4;

__device__ __forceinline__ ushort f2bf(float f) {
    union { __hip_bfloat16 h; ushort u; } cv;
    cv.h = __float2bfloat16(f);
    return cv.u;
}

// ---------------------------------------------------------------------------
// Kernel 0a: convert+transpose Wq|Wk|Wv (fp32 [1024][64] each) -> WT bf16 [192][1024]
// ---------------------------------------------------------------------------
__global__ void wcvt_kernel(const float* __restrict__ Wq,
                            const float* __restrict__ Wk,
                            const float* __restrict__ Wv,
                            ushort* __restrict__ WT)
{
    const int n  = blockIdx.x;          // 0..191
    const int o  = n >> 6;
    const int nn = n & 63;
    const float* W = (o == 0) ? Wq : (o == 1) ? Wk : Wv;
    #pragma unroll
    for (int i = 0; i < 4; i++) {
        int k = threadIdx.x + i * 256;
        WT[(size_t)n * DIM_D + k] = f2bf(W[(size_t)k * DIM_KH + nn]);
    }
}

// ---------------------------------------------------------------------------
// Kernel 0b: convert+transpose Wo (fp32 [64][1024]) -> WoT bf16 [1024][64]
// ---------------------------------------------------------------------------
__global__ void wocvt_kernel(const float* __restrict__ Wo, ushort* __restrict__ WoT)
{
    const int tid = threadIdx.x;
    const int n = blockIdx.x * 4 + (tid >> 6);   // 0..1023
    const int k = tid & 63;
    WoT[(size_t)n * DIM_KH + k] = f2bf(Wo[(size_t)k * DIM_D + n]);
}

// ---------------------------------------------------------------------------
// Kernel 1: QKV projection with bf16 MFMA. (unchanged)
// ---------------------------------------------------------------------------
__global__ __launch_bounds__(256, 2) void qkv_mfma(
    const float* __restrict__ X, const ushort* __restrict__ WT,
    const float* __restrict__ bq, const float* __restrict__ bk,
    const float* __restrict__ bv,
    ushort* __restrict__ Qb, ushort* __restrict__ Kb, ushort* __restrict__ Vb)
{
    const int tid = threadIdx.x;
    const int m0  = blockIdx.x * 64;
    const int o   = blockIdx.y;          // 0=Q 1=K 2=V

    __shared__ ushort Xs[64 * 64];       // [row][k], XOR-swizzled
    __shared__ ushort Wls[64 * 64];      // [n][k],   XOR-swizzled

    const int w  = tid >> 6;
    const int l  = tid & 63;
    const int ql = l & 15;
    const int g  = (l >> 4) & 3;
    const int swz = (ql & 7) << 3;

    floatx4 acc[4];
    #pragma unroll
    for (int fn = 0; fn < 4; fn++) acc[fn] = (floatx4){0.f, 0.f, 0.f, 0.f};

    for (int k0 = 0; k0 < DIM_D; k0 += 64) {
        __syncthreads();
        #pragma unroll
        for (int i = 0; i < 4; i++) {
            int idx = tid + i * 256;
            int row = idx >> 4;
            int c4  = idx & 15;
            float4 x4 = *reinterpret_cast<const float4*>(
                X + (size_t)(m0 + row) * DIM_D + k0 + c4 * 4);
            uint2 p;
            p.x = (uint)f2bf(x4.x) | ((uint)f2bf(x4.y) << 16);
            p.y = (uint)f2bf(x4.z) | ((uint)f2bf(x4.w) << 16);
            int addr = row * 64 + ((c4 * 4) ^ ((row & 7) << 3));
            *reinterpret_cast<uint2*>(&Xs[addr]) = p;
        }
        #pragma unroll
        for (int i = 0; i < 2; i++) {
            int idx = tid + i * 256;
            int n   = idx >> 3;
            int ch  = idx & 7;
            uint4 v = *reinterpret_cast<const uint4*>(
                WT + (size_t)(o * 64 + n) * DIM_D + k0 + ch * 8);
            int addr = n * 64 + ((ch * 8) ^ ((n & 7) << 3));
            *reinterpret_cast<uint4*>(&Wls[addr]) = v;
        }
        __syncthreads();

        #pragma unroll
        for (int kk = 0; kk < 2; kk++) {
            short8 a = *reinterpret_cast<const short8*>(
                &Xs[(16 * w + ql) * 64 + ((kk * 32 + g * 8) ^ swz)]);
            #pragma unroll
            for (int fn = 0; fn < 4; fn++) {
                short8 b = *reinterpret_cast<const short8*>(
                    &Wls[(16 * fn + ql) * 64 + ((kk * 32 + g * 8) ^ swz)]);
                acc[fn] = __builtin_amdgcn_mfma_f32_16x16x32_bf16(a, b, acc[fn], 0, 0, 0);
            }
        }
    }

    const float* bias = (o == 0) ? bq : (o == 1) ? bk : bv;
    ushort* O = (o == 0) ? Qb : (o == 1) ? Kb : Vb;
    float bvreg[4];
    #pragma unroll
    for (int fn = 0; fn < 4; fn++) bvreg[fn] = bias[16 * fn + ql];

    #pragma unroll
    for (int fn = 0; fn < 4; fn++) {
        #pragma unroll
        for (int r = 0; r < 4; r++) {
            int row = m0 + 16 * w + 4 * g + r;
            O[(size_t)row * DIM_KH + 16 * fn + ql] = f2bf(acc[fn][r] + bvreg[fn]);
        }
    }
}

// ---------------------------------------------------------------------------
// Kernel 2: flash attention, bf16 MFMA, split-KV. Grid (q-tiles, KVSPLIT, batch).
// Each block: 64 q-rows x 512 keys. Writes unnormalized partial O (fp32) + m,l.
// VTs swizzle: (dim&15)<<2 -> conflict-free transpose-write and PV read.
// ---------------------------------------------------------------------------
__global__ __launch_bounds__(256) void attn_mfma(
    const ushort* __restrict__ Qb, const ushort* __restrict__ Kb,
    const ushort* __restrict__ Vb,
    float* __restrict__ Opart, float* __restrict__ Ml)
{
    const int tid = threadIdx.x;
    const int w   = tid >> 6;
    const int l   = tid & 63;
    const int ql  = l & 15;
    const int g   = (l >> 4) & 3;
    const int q0  = blockIdx.x * 64;
    const int s   = blockIdx.y;          // KV split
    const int b   = blockIdx.z;
    const int swzq = (ql & 7) << 3;

    __shared__ ushort Ks[64 * 64];   // [key][dim], swizzled by key (row&7)<<3
    __shared__ ushort VTs[64 * 64];  // [dim][key], swizzled by (dim&15)<<2

    short8 qf[2];
    #pragma unroll
    for (int kk = 0; kk < 2; kk++) {
        qf[kk] = *reinterpret_cast<const short8*>(
            Qb + ((size_t)(b * SEQ + q0 + 16 * w + ql)) * DIM_KH + kk * 32 + g * 8);
    }

    floatx4 accv[4];
    #pragma unroll
    for (int fd = 0; fd < 4; fd++) accv[fd] = (floatx4){0.f, 0.f, 0.f, 0.f};
    float m_run = -3.0e38f, l_run = 0.f;

    const ushort* Kbb = Kb + (size_t)b * SEQ * DIM_KH;
    const ushort* Vbb = Vb + (size_t)b * SEQ * DIM_KH;
    const int t_begin = s * KEYS_PER_SPLIT;
    const int t_end   = t_begin + KEYS_PER_SPLIT;

    for (int t0 = t_begin; t0 < t_end; t0 += 64) {
        __syncthreads();
        // stage K tile [64][64]
        #pragma unroll
        for (int i = 0; i < 2; i++) {
            int idx = tid + i * 256;
            int row = idx >> 3;
            int ch  = idx & 7;
            uint4 v = *reinterpret_cast<const uint4*>(
                Kbb + (size_t)(t0 + row) * DIM_KH + ch * 8);
            *reinterpret_cast<uint4*>(&Ks[row * 64 + ((ch * 8) ^ ((row & 7) << 3))]) = v;
        }
        // stage V^T tile via 4x4 register transpose
        {
            int kg = tid >> 4, dg = tid & 15;
            int key0 = kg * 4, dim0 = dg * 4;
            uint2 vr[4];
            #pragma unroll
            for (int i = 0; i < 4; i++)
                vr[i] = *reinterpret_cast<const uint2*>(
                    Vbb + (size_t)(t0 + key0 + i) * DIM_KH + dim0);
            #pragma unroll
            for (int j = 0; j < 4; j++) {
                uint e0 = (j == 0) ? (vr[0].x & 0xffffu) : (j == 1) ? (vr[0].x >> 16)
                        : (j == 2) ? (vr[0].y & 0xffffu) : (vr[0].y >> 16);
                uint e1 = (j == 0) ? (vr[1].x & 0xffffu) : (j == 1) ? (vr[1].x >> 16)
                        : (j == 2) ? (vr[1].y & 0xffffu) : (vr[1].y >> 16);
                uint e2 = (j == 0) ? (vr[2].x & 0xffffu) : (j == 1) ? (vr[2].x >> 16)
                        : (j == 2) ? (vr[2].y & 0xffffu) : (vr[2].y >> 16);
                uint e3 = (j == 0) ? (vr[3].x & 0xffffu) : (j == 1) ? (vr[3].x >> 16)
                        : (j == 2) ? (vr[3].y & 0xffffu) : (vr[3].y >> 16);
                uint2 p; p.x = e0 | (e1 << 16); p.y = e2 | (e3 << 16);
                int dim = dim0 + j;
                int addr = dim * 64 + (key0 ^ ((dim & 15) << 2));
                *reinterpret_cast<uint2*>(&VTs[addr]) = p;
            }
        }
        __syncthreads();

        floatx4 sfrag[4];
        #pragma unroll
        for (int f = 0; f < 4; f++) {
            sfrag[f] = (floatx4){0.f, 0.f, 0.f, 0.f};
            #pragma unroll
            for (int kk = 0; kk < 2; kk++) {
                short8 a = *reinterpret_cast<const short8*>(
                    &Ks[(16 * f + ql) * 64 + ((kk * 32 + g * 8) ^ swzq)]);
                sfrag[f] = __builtin_amdgcn_mfma_f32_16x16x32_bf16(a, qf[kk], sfrag[f], 0, 0, 0);
            }
        }

        float mt = -3.0e38f;
        #pragma unroll
        for (int f = 0; f < 4; f++)
            #pragma unroll
            for (int r = 0; r < 4; r++) mt = fmaxf(mt, sfrag[f][r]);
        mt = fmaxf(mt, __shfl_xor(mt, 16));
        mt = fmaxf(mt, __shfl_xor(mt, 32));
        float m_new = fmaxf(m_run, mt);
        float sc = __expf((m_run - m_new) * 0.125f);
        float psum = 0.f;
        ushort pb[4][4];
        #pragma unroll
        for (int f = 0; f < 4; f++)
            #pragma unroll
            for (int r = 0; r < 4; r++) {
                float p = __expf((sfrag[f][r] - m_new) * 0.125f);
                pb[f][r] = f2bf(p);
                psum += p;
            }
        psum += __shfl_xor(psum, 16);
        psum += __shfl_xor(psum, 32);
        l_run = l_run * sc + psum;
        m_run = m_new;

        float s0 = __shfl(sc, 4 * g + 0);
        float s1 = __shfl(sc, 4 * g + 1);
        float s2 = __shfl(sc, 4 * g + 2);
        float s3 = __shfl(sc, 4 * g + 3);
        #pragma unroll
        for (int fd = 0; fd < 4; fd++) {
            accv[fd][0] *= s0; accv[fd][1] *= s1;
            accv[fd][2] *= s2; accv[fd][3] *= s3;
        }

        short8 pa_lo, pa_hi;
        pa_lo[0] = (short)pb[0][0]; pa_lo[1] = (short)pb[0][1];
        pa_lo[2] = (short)pb[0][2]; pa_lo[3] = (short)pb[0][3];
        pa_lo[4] = (short)pb[1][0]; pa_lo[5] = (short)pb[1][1];
        pa_lo[6] = (short)pb[1][2]; pa_lo[7] = (short)pb[1][3];
        pa_hi[0] = (short)pb[2][0]; pa_hi[1] = (short)pb[2][1];
        pa_hi[2] = (short)pb[2][2]; pa_hi[3] = (short)pb[2][3];
        pa_hi[4] = (short)pb[3][0]; pa_hi[5] = (short)pb[3][1];
        pa_hi[6] = (short)pb[3][2]; pa_hi[7] = (short)pb[3][3];

        #pragma unroll
        for (int fd = 0; fd < 4; fd++) {
            int dim = 16 * fd + ql;
            int base = dim * 64;
            int sw = (dim & 15) << 2;
            short4v v0 = *reinterpret_cast<const short4v*>(&VTs[base + ((4 * g) ^ sw)]);
            short4v v1 = *reinterpret_cast<const short4v*>(&VTs[base + ((16 + 4 * g) ^ sw)]);
            short8 bb;
            bb[0] = v0[0]; bb[1] = v0[1]; bb[2] = v0[2]; bb[3] = v0[3];
            bb[4] = v1[0]; bb[5] = v1[1]; bb[6] = v1[2]; bb[7] = v1[3];
            accv[fd] = __builtin_amdgcn_mfma_f32_16x16x32_bf16(pa_lo, bb, accv[fd], 0, 0, 0);
            short4v v2 = *reinterpret_cast<const short4v*>(&VTs[base + ((32 + 4 * g) ^ sw)]);
            short4v v3 = *reinterpret_cast<const short4v*>(&VTs[base + ((48 + 4 * g) ^ sw)]);
            short8 bb2;
            bb2[0] = v2[0]; bb2[1] = v2[1]; bb2[2] = v2[2]; bb2[3] = v2[3];
            bb2[4] = v3[0]; bb2[5] = v3[1]; bb2[6] = v3[2]; bb2[7] = v3[3];
            accv[fd] = __builtin_amdgcn_mfma_f32_16x16x32_bf16(pa_hi, bb2, accv[fd], 0, 0, 0);
        }
    }

    // epilogue: write unnormalized partial O + (m,l) per q-row
    const size_t rid0 = (size_t)b * SEQ + q0;
    if (g == 0) {
        size_t rid = rid0 + 16 * w + ql;
        Ml[((size_t)s * NROWS + rid) * 2 + 0] = m_run;
        Ml[((size_t)s * NROWS + rid) * 2 + 1] = l_run;
    }
    #pragma unroll
    for (int fd = 0; fd < 4; fd++) {
        int col = 16 * fd + ql;
        size_t rbase = (size_t)s * NROWS + rid0 + 16 * w + 4 * g;
        Opart[(rbase + 0) * DIM_KH + col] = accv[fd][0];
        Opart[(rbase + 1) * DIM_KH + col] = accv[fd][1];
        Opart[(rbase + 2) * DIM_KH + col] = accv[fd][2];
        Opart[(rbase + 3) * DIM_KH + col] = accv[fd][3];
    }
}

// ---------------------------------------------------------------------------
// Kernel 2b: combine KV splits -> AVb (bf16). 16 rows/block, 16 lanes/row.
// ---------------------------------------------------------------------------
__global__ __launch_bounds__(256) void attn_combine(
    const float* __restrict__ Opart, const float* __restrict__ Ml,
    ushort* __restrict__ AVb)
{
    const int tid = threadIdx.x;
    const size_t rid = (size_t)blockIdx.x * 16 + (tid >> 4);
    const int d0 = (tid & 15) * 4;

    float m[KVSPLIT], lv[KVSPLIT];
    float M = -3.0e38f;
    #pragma unroll
    for (int s = 0; s < KVSPLIT; s++) {
        m[s]  = Ml[((size_t)s * NROWS + rid) * 2 + 0];
        lv[s] = Ml[((size_t)s * NROWS + rid) * 2 + 1];
        M = fmaxf(M, m[s]);
    }
    float wsum = 0.f;
    float o0 = 0.f, o1 = 0.f, o2 = 0.f, o3 = 0.f;
    #pragma unroll
    for (int s = 0; s < KVSPLIT; s++) {
        float wgt = __expf((m[s] - M) * 0.125f);
        wsum = fmaf(wgt, lv[s], wsum);
        float4 a = *reinterpret_cast<const float4*>(
            Opart + ((size_t)s * NROWS + rid) * DIM_KH + d0);
        o0 = fmaf(wgt, a.x, o0);
        o1 = fmaf(wgt, a.y, o1);
        o2 = fmaf(wgt, a.z, o2);
        o3 = fmaf(wgt, a.w, o3);
    }
    float inv = 1.0f / wsum;
    uint2 p;
    p.x = (uint)f2bf(o0 * inv) | ((uint)f2bf(o1 * inv) << 16);
    p.y = (uint)f2bf(o2 * inv) | ((uint)f2bf(o3 * inv) << 16);
    *reinterpret_cast<uint2*>(AVb + rid * DIM_KH + d0) = p;
}

// ---------------------------------------------------------------------------
// Kernel 3: out = LayerNorm(X + AV @ Wo + bo) * gamma + beta, bf16 MFMA. (unchanged)
// ---------------------------------------------------------------------------
__global__ __launch_bounds__(256) void out_mfma(
    const float* __restrict__ X, const ushort* __restrict__ AVb,
    const ushort* __restrict__ WoT, const float* __restrict__ bo,
    const float* __restrict__ gamma, const float* __restrict__ beta,
    float* __restrict__ Out)
{
    const int tid = threadIdx.x;
    const int w   = tid >> 6;
    const int l   = tid & 63;
    const int ql  = l & 15;
    const int g   = (l >> 4) & 3;
    const int row = blockIdx.x * 16 + ql;
    const int c0  = w * 256;

    __shared__ float redS[4][16];
    __shared__ float redQ[4][16];

    short8 bf0 = *reinterpret_cast<const short8*>(AVb + (size_t)row * DIM_KH + g * 8);
    short8 bf1 = *reinterpret_cast<const short8*>(AVb + (size_t)row * DIM_KH + 32 + g * 8);

    floatx4 acc[16];
    #pragma unroll
    for (int ft = 0; ft < 16; ft++) {
        const ushort* ap = WoT + (size_t)(c0 + 16 * ft + ql) * DIM_KH + g * 8;
        short8 a0 = *reinterpret_cast<const short8*>(ap);
        short8 a1 = *reinterpret_cast<const short8*>(ap + 32);
        floatx4 z = (floatx4){0.f, 0.f, 0.f, 0.f};
        z = __builtin_amdgcn_mfma_f32_16x16x32_bf16(a0, bf0, z, 0, 0, 0);
        z = __builtin_amdgcn_mfma_f32_16x16x32_bf16(a1, bf1, z, 0, 0, 0);
        acc[ft] = z;
    }

    float s = 0.f, sq = 0.f;
    #pragma unroll
    for (int ft = 0; ft < 16; ft++) {
        int col = c0 + 16 * ft + 4 * g;
        float4 x4 = *reinterpret_cast<const float4*>(X + (size_t)row * DIM_D + col);
        float4 b4 = *reinterpret_cast<const float4*>(bo + col);
        float y0 = acc[ft][0] + x4.x + b4.x;
        float y1 = acc[ft][1] + x4.y + b4.y;
        float y2 = acc[ft][2] + x4.z + b4.z;
        float y3 = acc[ft][3] + x4.w + b4.w;
        acc[ft][0] = y0; acc[ft][1] = y1; acc[ft][2] = y2; acc[ft][3] = y3;
        s  += (y0 + y1) + (y2 + y3);
        sq += fmaf(y0, y0, fmaf(y1, y1, fmaf(y2, y2, y3 * y3)));
    }
    s  += __shfl_xor(s, 16);  s  += __shfl_xor(s, 32);
    sq += __shfl_xor(sq, 16); sq += __shfl_xor(sq, 32);
    if (l < 16) { redS[w][ql] = s; redQ[w][ql] = sq; }
    __syncthreads();
    float st = (redS[0][ql] + redS[1][ql]) + (redS[2][ql] + redS[3][ql]);
    float qt = (redQ[0][ql] + redQ[1][ql]) + (redQ[2][ql] + redQ[3][ql]);
    float mu  = st * (1.0f / 1024.0f);
    float var = fmaf(qt, (1.0f / 1024.0f), -mu * mu);
    float inv = rsqrtf(var + 1e-5f);

    #pragma unroll
    for (int ft = 0; ft < 16; ft++) {
        int col = c0 + 16 * ft + 4 * g;
        float4 g4  = *reinterpret_cast<const float4*>(gamma + col);
        float4 be4 = *reinterpret_cast<const float4*>(beta + col);
        float4 ov;
        ov.x = fmaf((acc[ft][0] - mu) * inv, g4.x, be4.x);
        ov.y = fmaf((acc[ft][1] - mu) * inv, g4.y, be4.y);
        ov.z = fmaf((acc[ft][2] - mu) * inv, g4.z, be4.z);
        ov.w = fmaf((acc[ft][3] - mu) * inv, g4.w, be4.w);
        *reinterpret_cast<float4*>(Out + (size_t)row * DIM_D + col) = ov;
    }
}

// ---------------------------------------------------------------------------
extern "C" void kernel_launch(void* const* d_in, const int* in_sizes, int n_in,
                              void* d_out, int out_size, void* d_ws, size_t ws_size,
                              hipStream_t stream)
{
    (void)in_sizes; (void)n_in; (void)out_size; (void)ws_size;
    const float* X     = (const float*)d_in[0];
    const float* Wq    = (const float*)d_in[1];
    const float* bq    = (const float*)d_in[2];
    const float* Wk    = (const float*)d_in[3];
    const float* bk    = (const float*)d_in[4];
    const float* Wv    = (const float*)d_in[5];
    const float* bv    = (const float*)d_in[6];
    const float* Wo    = (const float*)d_in[7];
    const float* bo    = (const float*)d_in[8];
    const float* gamma = (const float*)d_in[9];
    const float* beta  = (const float*)d_in[10];
    float* Out = (float*)d_out;

    ushort* Qb  = (ushort*)d_ws;                          // 2 MB bf16
    ushort* Kb  = Qb + (size_t)NROWS * DIM_KH;            // 2 MB
    ushort* Vb  = Kb + (size_t)NROWS * DIM_KH;            // 2 MB
    ushort* AVb = Vb + (size_t)NROWS * DIM_KH;            // 2 MB
    ushort* WT  = AVb + (size_t)NROWS * DIM_KH;           // 384 KB
    ushort* WoT = WT + (size_t)192 * DIM_D;               // 128 KB
    float*  Opart = (float*)(WoT + (size_t)DIM_D * DIM_KH);        // 16 MB
    float*  Ml    = Opart + (size_t)KVSPLIT * NROWS * DIM_KH;      // 512 KB

    wcvt_kernel<<<192, 256, 0, stream>>>(Wq, Wk, Wv, WT);
    wocvt_kernel<<<256, 256, 0, stream>>>(Wo, WoT);
    qkv_mfma<<<dim3(256, 3), 256, 0, stream>>>(X, WT, bq, bk, bv, Qb, Kb, Vb);
    attn_mfma<<<dim3(SEQ/64, KVSPLIT, BATCH), 256, 0, stream>>>(Qb, Kb, Vb, Opart, Ml);
    attn_combine<<<NROWS/16, 256, 0, stream>>>(Opart, Ml, AVb);
    out_mfma<<<NROWS/16, 256, 0, stream>>>(X, AVb, WoT, bo, gamma, beta, Out);
}